// Round 4
// baseline (391.727 us; speedup 1.0000x reference)
//
#include <hip/hip_runtime.h>

// GroupLinearBlock: out = einsum('nhd,hdf', (rmsnorm_h(x@W) + b)/sqrt2, K)
// Design: cvt x->bf16 prep pass; GEMM1 = 256x256 tile, BK=32, 8 waves,
// 3-deep rotating LDS buffers, global_load_lds both operands, counted
// vmcnt(4) + raw s_barrier (loads span barriers); fused per-wave
// RMSNorm + bias-blend + GEMM2 epilogue (one head per wave).

typedef __attribute__((ext_vector_type(8))) __bf16 bf16x8;
typedef __attribute__((ext_vector_type(4))) float f32x4;
typedef __attribute__((ext_vector_type(8))) unsigned short ushort8;

__device__ __forceinline__ unsigned short bfbits(float f) {
  return __builtin_bit_cast(unsigned short, (__bf16)f);
}
__device__ __forceinline__ f32x4 mfma_bf16(bf16x8 a, bf16x8 b, f32x4 c) {
  return __builtin_amdgcn_mfma_f32_16x16x32_bf16(a, b, c, 0, 0, 0);
}
__device__ __forceinline__ void gl_lds16(const void* g, void* l) {
  __builtin_amdgcn_global_load_lds(
      (const __attribute__((address_space(1))) unsigned int*)g,
      (__attribute__((address_space(3))) unsigned int*)l, 16, 0, 0);
}

// ---- prep: x f32 -> bf16 (chunk of rows) ----
__global__ void cvt_x(const float* __restrict__ x, unsigned short* __restrict__ xb, int n8) {
  int i = blockIdx.x * blockDim.x + threadIdx.x;
  const int stride = gridDim.x * blockDim.x;
  for (; i < n8; i += stride) {
    f32x4 a = *reinterpret_cast<const f32x4*>(x + (size_t)i * 8);
    f32x4 b = *reinterpret_cast<const f32x4*>(x + (size_t)i * 8 + 4);
    ushort8 v;
    v[0] = bfbits(a[0]); v[1] = bfbits(a[1]); v[2] = bfbits(a[2]); v[3] = bfbits(a[3]);
    v[4] = bfbits(b[0]); v[5] = bfbits(b[1]); v[6] = bfbits(b[2]); v[7] = bfbits(b[3]);
    *reinterpret_cast<ushort8*>(xb + (size_t)i * 8) = v;
  }
}

// ---- prep: w_lin [k][n] f32 -> wb = exact LDS image, [ct(4)][t(32)][chunk(1024)x16B]
// LDS tile layout: [kh(2)][col(256)][32B], slot-swizzled: s' = s ^ ((col>>2)&1).
__global__ void prep_w(const float* __restrict__ w, unsigned short* __restrict__ wb) {
  const int g = blockIdx.x * 256 + threadIdx.x;   // 0..131071 chunk id
  const int ct = g >> 15;
  const int rem = g & 32767;
  const int t = rem >> 10;
  const int c = rem & 1023;
  const int kh = c >> 9, r = (c >> 1) & 255, s = c & 1;
  const int col = ct * 256 + r;
  const int k0 = t * 32 + kh * 16 + ((s ^ ((r >> 2) & 1)) << 3);
  ushort8 v;
  #pragma unroll
  for (int j = 0; j < 8; ++j) v[j] = bfbits(w[(size_t)(k0 + j) * 1024 + col]);
  *reinterpret_cast<ushort8*>(wb + (size_t)g * 8) = v;
}

// ---- prep: kernel [16][d][f] f32 -> kt [16][f][d] bf16 ----
__global__ void transpose_k(const float* __restrict__ kin, unsigned short* __restrict__ kt) {
  __shared__ float tile[64][65];
  const int h = blockIdx.x;
  const int t = threadIdx.x;
  #pragma unroll
  for (int i = 0; i < 16; ++i) {
    int idx = i * 256 + t;
    tile[idx >> 6][idx & 63] = kin[(size_t)h * 4096 + idx];
  }
  __syncthreads();
  #pragma unroll
  for (int i = 0; i < 16; ++i) {
    int idx = i * 256 + t;
    kt[(size_t)h * 4096 + idx] = bfbits(tile[idx & 63][idx >> 6]);
  }
}

// ---- main: tile 256x256, BK=32, 512 threads (8 waves 2Mx4N) ----
__global__ __launch_bounds__(512, 2)
void fused_main(const unsigned short* __restrict__ xb,
                const float* __restrict__ nbias,
                const unsigned short* __restrict__ wb,
                const unsigned short* __restrict__ ktg,
                float* __restrict__ out,
                long row0_base, int nb8)
{
  // 96KB: A bufs 3x16KB at 0; B bufs 3x16KB at 49152. Epilogue reuses [0,64K) as y.
  __shared__ __align__(16) unsigned char smem[98304];
  const int tid = threadIdx.x;
  const int wv = tid >> 6, lane = tid & 63, l15 = lane & 15, lg = lane >> 4;
  const int wr = wv >> 2, wc = wv & 3;          // wave: rows wr*128, cols wc*64
  const int bid = blockIdx.x;
  const int v = (bid & 7) * nb8 + (bid >> 3);   // bijective XCD grouping
  const int rt = v >> 2, ct = v & 3;
  const long grow0 = row0_base + (long)rt * 256;
  const size_t lrow0 = (size_t)rt * 256;        // row within xb chunk

  // staging: thread u handles chunks P=u*16 (kh=0) and P=8192+u*16 (kh=1)
  const int u = tid;
  const int sr = u >> 1, ss = u & 1;
  const int slog = (ss ^ ((sr >> 2) & 1)) << 4;            // pre-swizzled src k-byte
  const char* asrc = (const char*)xb + (lrow0 + sr) * 2048 + slog;
  const char* bsrc = (const char*)wb + (size_t)ct * 524288 + (size_t)u * 16;

  // fragment-read offsets (2-way bank aliasing only)
  const int fswz = (((lg & 1) ^ ((l15 >> 2) & 1)) << 4);
  const int aoff = (lg >> 1) * 8192 + (wr * 128 + l15) * 32 + fswz;
  const int boff = (lg >> 1) * 8192 + (wc * 64 + l15) * 32 + fswz;

  f32x4 acc[8][4];
  const f32x4 z4 = {0.f, 0.f, 0.f, 0.f};
  #pragma unroll
  for (int mi = 0; mi < 8; ++mi)
    #pragma unroll
    for (int ni = 0; ni < 4; ++ni) acc[mi][ni] = z4;

  auto stage = [&](int t) {
    const int b = t % 3;
    unsigned char* Ab = smem + b * 16384;
    unsigned char* Bb = smem + 49152 + b * 16384;
    const char* as = asrc + (size_t)t * 64;
    const char* bs = bsrc + (size_t)t * 16384;
    gl_lds16(as,        Ab + u * 16);
    gl_lds16(as + 32,   Ab + 8192 + u * 16);
    gl_lds16(bs,        Bb + u * 16);
    gl_lds16(bs + 8192, Bb + 8192 + u * 16);
  };
  auto compute = [&](int t) {
    const int b = t % 3;
    const unsigned char* Ab = smem + b * 16384;
    const unsigned char* Bb = smem + 49152 + b * 16384;
    bf16x8 af[8], bq[4];
    #pragma unroll
    for (int mi = 0; mi < 8; ++mi)
      af[mi] = *reinterpret_cast<const bf16x8*>(Ab + aoff + mi * 512);
    #pragma unroll
    for (int ni = 0; ni < 4; ++ni)
      bq[ni] = *reinterpret_cast<const bf16x8*>(Bb + boff + ni * 512);
    __builtin_amdgcn_s_setprio(1);
    #pragma unroll
    for (int mi = 0; mi < 8; ++mi)
      #pragma unroll
      for (int ni = 0; ni < 4; ++ni)
        acc[mi][ni] = mfma_bf16(af[mi], bq[ni], acc[mi][ni]);
    __builtin_amdgcn_s_setprio(0);
  };

  // prologue: tiles 0,1 staged; enter loop with tile0 landed, tile1 in flight
  stage(0); stage(1);
  asm volatile("s_waitcnt vmcnt(4)" ::: "memory");
  __builtin_amdgcn_sched_barrier(0);
  __builtin_amdgcn_s_barrier();
  __builtin_amdgcn_sched_barrier(0);

  #pragma unroll
  for (int t = 0; t < 32; ++t) {
    if (t + 2 < 32) { stage(t + 2); __builtin_amdgcn_sched_barrier(0); }
    compute(t);
    if (t < 31) {
      __builtin_amdgcn_sched_barrier(0);
      if (t + 2 < 32) asm volatile("s_waitcnt vmcnt(4)" ::: "memory");
      else            asm volatile("s_waitcnt vmcnt(0)" ::: "memory");
      __builtin_amdgcn_sched_barrier(0);
      __builtin_amdgcn_s_barrier();
      __builtin_amdgcn_sched_barrier(0);
    }
  }
  __builtin_amdgcn_sched_barrier(0);
  __syncthreads();   // full drain; repurpose LDS as y

  // ---- epilogue: RMSNorm + bias blend + GEMM2, one head per wave ----
  const int h = ct * 4 + wc;
  const unsigned short* ktp = ktg + (size_t)h * 4096;
  bf16x8 b2[4][2];
  #pragma unroll
  for (int ff = 0; ff < 4; ++ff)
    #pragma unroll
    for (int ks = 0; ks < 2; ++ks)
      b2[ff][ks] = *reinterpret_cast<const bf16x8*>(ktp + (ff * 16 + l15) * 64 + ks * 32 + lg * 8);

  unsigned char* yw = smem + wv * 8192;          // per-wave 64 rows x 128B, swizzled
  const float* bb = nbias + (size_t)(grow0 + wr * 128) * 1024 + h * 64;

  #pragma unroll
  for (int hf = 0; hf < 2; ++hf) {
    #pragma unroll
    for (int mi4 = 0; mi4 < 4; ++mi4) {
      const int mi = hf * 4 + mi4;
      float ss4[4];
      #pragma unroll
      for (int r = 0; r < 4; ++r) {
        float p = 0.f;
        #pragma unroll
        for (int ni = 0; ni < 4; ++ni) { const float q = acc[mi][ni][r]; p += q * q; }
        ss4[r] = p;
      }
      #pragma unroll
      for (int s = 1; s < 16; s <<= 1)
        #pragma unroll
        for (int r = 0; r < 4; ++r) ss4[r] += __shfl_xor(ss4[r], s, 64);
      #pragma unroll
      for (int r = 0; r < 4; ++r) {
        const float rs = rsqrtf(ss4[r] * 0.015625f + 1e-6f);
        const int rl = mi4 * 16 + lg * 4 + r;                   // row in 64-half
        const float* bp = bb + (size_t)(hf * 64 + rl) * 1024;
        #pragma unroll
        for (int ni = 0; ni < 4; ++ni) {
          const float y = (acc[mi][ni][r] * rs + bp[ni * 16 + l15]) * 0.70710678118654752f;
          const int cb = ((ni * 16 + l15) * 2) ^ ((rl & 7) << 4);
          *reinterpret_cast<unsigned short*>(yw + rl * 128 + cb) = bfbits(y);
        }
      }
    }
    #pragma unroll
    for (int m2 = 0; m2 < 4; ++m2) {
      f32x4 a2[4] = {z4, z4, z4, z4};
      const int row = m2 * 16 + l15;
      #pragma unroll
      for (int ks = 0; ks < 2; ++ks) {
        const int cb = (ks * 64 + lg * 16) ^ ((row & 7) << 4);
        bf16x8 a = *reinterpret_cast<const bf16x8*>(yw + row * 128 + cb);
        #pragma unroll
        for (int ff = 0; ff < 4; ++ff) a2[ff] = mfma_bf16(a, b2[ff][ks], a2[ff]);
      }
      float* ob = out + (size_t)(grow0 + wr * 128 + hf * 64 + m2 * 16 + lg * 4) * 1024
                      + ct * 256 + wc * 64 + l15;
      #pragma unroll
      for (int ff = 0; ff < 4; ++ff)
        #pragma unroll
        for (int r = 0; r < 4; ++r)
          ob[(size_t)r * 1024 + ff * 16] = a2[ff][r];
    }
  }
}

extern "C" void kernel_launch(void* const* d_in, const int* in_sizes, int n_in,
                              void* d_out, int out_size, void* d_ws, size_t ws_size,
                              hipStream_t stream) {
  const float* x  = (const float*)d_in[0];   // [65536][1024]
  const float* nb = (const float*)d_in[1];   // [65536][16][64]
  const float* wl = (const float*)d_in[2];   // [1024][1024]
  const float* kr = (const float*)d_in[3];   // [16][64][64]
  float* out = (float*)d_out;

  unsigned short* wb = (unsigned short*)d_ws;                 // 2 MB blocked W image
  unsigned short* kt = wb + 1048576;                          // 128 KB
  const size_t xb_off = 2228224;                              // 2.125 MB, 16B-aligned
  unsigned short* xb = (unsigned short*)((char*)d_ws + xb_off);

  long rows_chunk;
  if (ws_size >= xb_off + 134217728ull) {
    rows_chunk = 65536;
  } else {
    size_t usable = ws_size > xb_off ? ws_size - xb_off : 0;
    rows_chunk = (long)(usable / 2048) & ~511L;
    if (rows_chunk < 512) rows_chunk = 512;   // assume ws >= ~3.3MB
  }

  hipLaunchKernelGGL(prep_w, dim3(512), dim3(256), 0, stream, wl, wb);
  hipLaunchKernelGGL(transpose_k, dim3(16), dim3(256), 0, stream, kr, kt);

  for (long r0 = 0; r0 < 65536; r0 += rows_chunk) {
    const long cr = (65536 - r0 < rows_chunk) ? (65536 - r0) : rows_chunk;
    hipLaunchKernelGGL(cvt_x, dim3(1024), dim3(256), 0, stream,
                       x + (size_t)r0 * 1024, xb, (int)(cr * 128));
    const int nblk = (int)(cr / 256) * 4;
    hipLaunchKernelGGL(fused_main, dim3(nblk), dim3(512), 0, stream,
                       xb, nb, wb, kt, out, r0, nblk / 8);
  }
}

// Round 5
// 330.461 us; speedup vs baseline: 1.1854x; 1.1854x over previous
//
#include <hip/hip_runtime.h>

// GroupLinearBlock: out = einsum('nhd,hdf', (rmsnorm_h(x@W) + b)/sqrt2, K)
// Single fused kernel: BM=128,BN=128,BK=32, 4 waves, 32KB LDS (3 blocks/CU).
// A: reg-staged f32->bf16 (load t+2, cvt+ds_write t+1). B: global_load_lds
// from pre-blocked bf16 W image. Counted vmcnt(4) + raw s_barrier so A-loads
// span barriers. Fused per-wave RMSNorm + bias-blend + GEMM2 epilogue.

typedef __attribute__((ext_vector_type(8))) __bf16 bf16x8;
typedef __attribute__((ext_vector_type(4))) float f32x4;
typedef __attribute__((ext_vector_type(8))) unsigned short ushort8;

__device__ __forceinline__ unsigned short bfbits(float f) {
  return __builtin_bit_cast(unsigned short, (__bf16)f);
}
__device__ __forceinline__ f32x4 mfma_bf16(bf16x8 a, bf16x8 b, f32x4 c) {
  return __builtin_amdgcn_mfma_f32_16x16x32_bf16(a, b, c, 0, 0, 0);
}
__device__ __forceinline__ void gl_lds16(const void* g, void* l) {
  __builtin_amdgcn_global_load_lds(
      (const __attribute__((address_space(1))) unsigned int*)g,
      (__attribute__((address_space(3))) unsigned int*)l, 16, 0, 0);
}

// ---- prep: w_lin [k][n] f32 -> wb[ct(8)][t(32)][kc(4)][col(128)][8] bf16
// (exact per-step LDS image: [kc][col][16B], flat-copy staging)
__global__ void prep_w2(const float* __restrict__ w, unsigned short* __restrict__ wb) {
  const int t = blockIdx.x, ct = blockIdx.y, col = threadIdx.x;   // 32 x 8, 128 thr
  #pragma unroll
  for (int kc = 0; kc < 4; ++kc) {
    ushort8 v;
    #pragma unroll
    for (int j = 0; j < 8; ++j)
      v[j] = bfbits(w[(size_t)(t * 32 + kc * 8 + j) * 1024 + ct * 128 + col]);
    *reinterpret_cast<ushort8*>(wb + (((size_t)(ct * 32 + t) * 4 + kc) * 128 + col) * 8) = v;
  }
}

// ---- prep: kernel [16][d][f] f32 -> kt [16][f][d] bf16 ----
__global__ void transpose_k(const float* __restrict__ kin, unsigned short* __restrict__ kt) {
  __shared__ float tile[64][65];
  const int h = blockIdx.x;
  const int t = threadIdx.x;
  #pragma unroll
  for (int i = 0; i < 16; ++i) {
    int idx = i * 256 + t;
    tile[idx >> 6][idx & 63] = kin[(size_t)h * 4096 + idx];
  }
  __syncthreads();
  #pragma unroll
  for (int i = 0; i < 16; ++i) {
    int idx = i * 256 + t;
    kt[(size_t)h * 4096 + idx] = bfbits(tile[idx & 63][idx >> 6]);
  }
}

// ---- main: 4096 blocks x 256 threads; tile 128x128, K=1024, BK=32 ----
__global__ __launch_bounds__(256, 3)
void fused_main(const float* __restrict__ x,
                const float* __restrict__ nbias,
                const unsigned short* __restrict__ wb,
                const unsigned short* __restrict__ ktg,
                float* __restrict__ out)
{
  // LDS 32KB: A bufs [0,8K),[8K,16K)  layout [kc(4)][row(128)][16B]
  //           B bufs [16K,24K),[24K,32K) layout [kc(4)][col(128)][16B]
  // Epilogue reuses [0,32K) as per-wave y (64x64 bf16, XOR-swizzled).
  __shared__ __align__(16) unsigned char smem[32768];
  const int tid = threadIdx.x;
  const int wv = tid >> 6, lane = tid & 63, l15 = lane & 15, lg = lane >> 4;
  const int wr = wv >> 1, wc = wv & 1;            // wave: rows wr*64, cols wc*64
  const int bid = blockIdx.x;
  const int gx = bid & 7, slot = bid >> 3;        // XCD grouping: per XCD,
  const int v = gx * 512 + slot;                  // 64 consecutive rt, ct fastest
  const int rt = v >> 3, ct = v & 7;
  const size_t row0 = (size_t)rt * 128;

  // A staging mapping: thread u -> row r=u>>1, k-half h=u&1 (16 f32 -> 16 bf16)
  const int sr = tid >> 1, sh = tid & 1;
  const float* agp = x + (row0 + sr) * 1024 + sh * 16;
  const unsigned char* wsrc =
      reinterpret_cast<const unsigned char*>(wb) + (size_t)ct * 262144;

  // fragment-read offsets: [kc=lg][row/col][16B] -> 16B-contig per lane
  const int aoff = lg * 2048 + (wr * 64 + l15) * 16;
  const int boff = lg * 2048 + (wc * 64 + l15) * 16;

  f32x4 acc[4][4];
  const f32x4 z4 = {0.f, 0.f, 0.f, 0.f};
  #pragma unroll
  for (int mi = 0; mi < 4; ++mi)
    #pragma unroll
    for (int ni = 0; ni < 4; ++ni) acc[mi][ni] = z4;

  f32x4 arg[2][4];   // two in-flight A register sets (16 f32 each, static idx)

  auto stageB = [&](int t, int bsel) {
    unsigned char* Bb = smem + 16384 + (bsel << 13);
    const unsigned char* bs = wsrc + (size_t)t * 8192;
    gl_lds16(bs + tid * 16,        Bb + tid * 16);
    gl_lds16(bs + 4096 + tid * 16, Bb + 4096 + tid * 16);
  };
  auto loadA = [&](int t, f32x4* dst) {
    const float* p = agp + t * 32;
    #pragma unroll
    for (int j = 0; j < 4; ++j) dst[j] = *reinterpret_cast<const f32x4*>(p + j * 4);
  };
  auto cvtwrA = [&](const f32x4* src, int bsel) {
    unsigned char* Ab = smem + (bsel << 13);
    ushort8 v0, v1;
    #pragma unroll
    for (int j = 0; j < 4; ++j) { v0[j] = bfbits(src[0][j]); v0[4 + j] = bfbits(src[1][j]); }
    #pragma unroll
    for (int j = 0; j < 4; ++j) { v1[j] = bfbits(src[2][j]); v1[4 + j] = bfbits(src[3][j]); }
    // k-half sh covers kc = 2*sh (elems 0..7) and kc = 2*sh+1 (elems 8..15)
    *reinterpret_cast<ushort8*>(Ab + (2 * sh) * 2048 + sr * 16)     = v0;
    *reinterpret_cast<ushort8*>(Ab + (2 * sh + 1) * 2048 + sr * 16) = v1;
  };
  auto compute = [&](int csel) {
    const unsigned char* Ab = smem + (csel << 13);
    const unsigned char* Bb = smem + 16384 + (csel << 13);
    bf16x8 af[4], bq[4];
    #pragma unroll
    for (int mi = 0; mi < 4; ++mi)
      af[mi] = *reinterpret_cast<const bf16x8*>(Ab + aoff + mi * 256);
    #pragma unroll
    for (int ni = 0; ni < 4; ++ni)
      bq[ni] = *reinterpret_cast<const bf16x8*>(Bb + boff + ni * 256);
    __builtin_amdgcn_s_setprio(1);
    #pragma unroll
    for (int mi = 0; mi < 4; ++mi)
      #pragma unroll
      for (int ni = 0; ni < 4; ++ni)
        acc[mi][ni] = mfma_bf16(af[mi], bq[ni], acc[mi][ni]);
    __builtin_amdgcn_s_setprio(0);
  };

  // ---- prologue ----
  stageB(0, 0);
  loadA(0, arg[0]);
  loadA(1, arg[1]);
  __builtin_amdgcn_sched_barrier(0);
  cvtwrA(arg[0], 0);     // auto-wait drains A(0) (and older B(0)); A(1) in flight
  asm volatile("s_waitcnt lgkmcnt(0)" ::: "memory");
  __builtin_amdgcn_sched_barrier(0);
  __builtin_amdgcn_s_barrier();
  __builtin_amdgcn_sched_barrier(0);

  // ---- main loop: 32 K-steps ----
  #pragma unroll
  for (int t = 0; t < 32; ++t) {
    const int c = t & 1, n = c ^ 1;
    if (t + 1 < 32) { stageB(t + 1, n); __builtin_amdgcn_sched_barrier(0); }
    if (t + 2 < 32) { loadA(t + 2, arg[c]); __builtin_amdgcn_sched_barrier(0); }

    compute(c);                         // 8 ds_read_b128 + 16 MFMA
    if (t + 1 < 32) cvtwrA(arg[n], n);  // auto vmcnt(6): A(t+1) only, rest fly

    if (t + 1 < 32) {
      asm volatile("s_waitcnt lgkmcnt(0)" ::: "memory");   // ds_writes done
      if (t + 2 < 32) asm volatile("s_waitcnt vmcnt(4)" ::: "memory");  // B(t+1) landed, A(t+2) flies
      else            asm volatile("s_waitcnt vmcnt(0)" ::: "memory");
      __builtin_amdgcn_sched_barrier(0);
      __builtin_amdgcn_s_barrier();
      __builtin_amdgcn_sched_barrier(0);
    }
  }
  __builtin_amdgcn_sched_barrier(0);
  __syncthreads();   // drain; repurpose LDS as y

  // ---- epilogue: per-head RMSNorm + bias blend -> y LDS -> GEMM2 ----
  const int h = ct * 2 + wc;
  unsigned short* yw = reinterpret_cast<unsigned short*>(smem) + wv * 4096;  // 64x64 swz
  const float* bb = nbias + (row0 + wr * 64) * 1024 + (size_t)h * 64 + l15;

  #pragma unroll
  for (int mi = 0; mi < 4; ++mi) {
    float ss[4];
    #pragma unroll
    for (int r = 0; r < 4; ++r) {
      float p = 0.f;
      #pragma unroll
      for (int ni = 0; ni < 4; ++ni) { const float q = acc[mi][ni][r]; p += q * q; }
      ss[r] = p;
    }
    #pragma unroll
    for (int s = 1; s < 16; s <<= 1)
      #pragma unroll
      for (int r = 0; r < 4; ++r) ss[r] += __shfl_xor(ss[r], s, 64);
    #pragma unroll
    for (int r = 0; r < 4; ++r) {
      const float rs = rsqrtf(ss[r] * 0.015625f + 1e-6f);
      const int rl = mi * 16 + lg * 4 + r;
      const float* bp = bb + (size_t)rl * 1024;
      #pragma unroll
      for (int ni = 0; ni < 4; ++ni) {
        const float y = (acc[mi][ni][r] * rs + bp[ni * 16]) * 0.70710678118654752f;
        yw[rl * 64 + ((ni * 16 + l15) ^ ((rl & 7) << 3))] = bfbits(y);
      }
    }
  }

  // GEMM2: y[64][64] @ ktg[h][f][d]
  const unsigned short* ktp = ktg + (size_t)h * 4096;
  bf16x8 b2[4][2];
  #pragma unroll
  for (int ff = 0; ff < 4; ++ff)
    #pragma unroll
    for (int ks = 0; ks < 2; ++ks)
      b2[ff][ks] = *reinterpret_cast<const bf16x8*>(ktp + (ff * 16 + l15) * 64 + ks * 32 + lg * 8);

  #pragma unroll
  for (int m2 = 0; m2 < 4; ++m2) {
    f32x4 a2[4] = {z4, z4, z4, z4};
    const int row = m2 * 16 + l15;
    #pragma unroll
    for (int ks = 0; ks < 2; ++ks) {
      bf16x8 a = *reinterpret_cast<const bf16x8*>(
          yw + row * 64 + ((ks * 32 + lg * 8) ^ ((row & 7) << 3)));
      #pragma unroll
      for (int ff = 0; ff < 4; ++ff) a2[ff] = mfma_bf16(a, b2[ff][ks], a2[ff]);
    }
    float* ob = out + (row0 + wr * 64 + m2 * 16 + lg * 4) * 1024 + ct * 128 + wc * 64 + l15;
    #pragma unroll
    for (int ff = 0; ff < 4; ++ff)
      #pragma unroll
      for (int r = 0; r < 4; ++r)
        ob[(size_t)r * 1024 + ff * 16] = a2[ff][r];
  }
}

extern "C" void kernel_launch(void* const* d_in, const int* in_sizes, int n_in,
                              void* d_out, int out_size, void* d_ws, size_t ws_size,
                              hipStream_t stream) {
  const float* x  = (const float*)d_in[0];   // [65536][1024]
  const float* nb = (const float*)d_in[1];   // [65536][16][64]
  const float* wl = (const float*)d_in[2];   // [1024][1024]
  const float* kr = (const float*)d_in[3];   // [16][64][64]
  float* out = (float*)d_out;

  unsigned short* wbp = (unsigned short*)d_ws;           // 2 MB blocked W image
  unsigned short* ktp = wbp + 1048576;                   // 128 KB

  hipLaunchKernelGGL(prep_w2, dim3(32, 8), dim3(128), 0, stream, wl, wbp);
  hipLaunchKernelGGL(transpose_k, dim3(16), dim3(256), 0, stream, kr, ktp);
  hipLaunchKernelGGL(fused_main, dim3(4096), dim3(256), 0, stream, x, nb, wbp, ktp, out);
}

// Round 6
// 321.450 us; speedup vs baseline: 1.2186x; 1.0280x over previous
//
#include <hip/hip_runtime.h>

// GroupLinearBlock: out = einsum('nhd,hdf', (rmsnorm_h(x@W) + b)/sqrt2, K)
// R6: pre-convert x -> bf16 (xb in ws). Main kernel = pure-bf16 m97 structure:
// BM=128,BN=128,BK=32, 4 waves, 32KB LDS dbuf (4-5 blocks/CU), A+B both via
// global_load_lds (A source pre-swizzled for conflict-free frag reads), plain
// 2-barrier loop (compiler-scheduled waits). Fused RMSNorm+bias+GEMM2 epilogue.

typedef __attribute__((ext_vector_type(8))) __bf16 bf16x8;
typedef __attribute__((ext_vector_type(4))) float f32x4;
typedef __attribute__((ext_vector_type(8))) unsigned short ushort8;

__device__ __forceinline__ unsigned short bfbits(float f) {
  return __builtin_bit_cast(unsigned short, (__bf16)f);
}
__device__ __forceinline__ f32x4 mfma_bf16(bf16x8 a, bf16x8 b, f32x4 c) {
  return __builtin_amdgcn_mfma_f32_16x16x32_bf16(a, b, c, 0, 0, 0);
}
__device__ __forceinline__ void gl_lds16(const void* g, void* l) {
  __builtin_amdgcn_global_load_lds(
      (const __attribute__((address_space(1))) unsigned int*)g,
      (__attribute__((address_space(3))) unsigned int*)l, 16, 0, 0);
}

// ---- prep: x f32 -> xb bf16 (full 65536x1024) ----
__global__ void cvt_x(const float* __restrict__ x, unsigned short* __restrict__ xb, int n8) {
  int i = blockIdx.x * blockDim.x + threadIdx.x;
  const int stride = gridDim.x * blockDim.x;
  for (; i < n8; i += stride) {
    f32x4 a = *reinterpret_cast<const f32x4*>(x + (size_t)i * 8);
    f32x4 b = *reinterpret_cast<const f32x4*>(x + (size_t)i * 8 + 4);
    ushort8 v;
    v[0] = bfbits(a[0]); v[1] = bfbits(a[1]); v[2] = bfbits(a[2]); v[3] = bfbits(a[3]);
    v[4] = bfbits(b[0]); v[5] = bfbits(b[1]); v[6] = bfbits(b[2]); v[7] = bfbits(b[3]);
    *reinterpret_cast<ushort8*>(xb + (size_t)i * 8) = v;
  }
}

// ---- prep: w_lin [k][n] f32 -> wb[ct(8)][t(32)][kc(4)][col(128)][8] bf16 ----
__global__ void prep_w2(const float* __restrict__ w, unsigned short* __restrict__ wb) {
  const int t = blockIdx.x, ct = blockIdx.y, col = threadIdx.x;   // 32 x 8, 128 thr
  #pragma unroll
  for (int kc = 0; kc < 4; ++kc) {
    ushort8 v;
    #pragma unroll
    for (int j = 0; j < 8; ++j)
      v[j] = bfbits(w[(size_t)(t * 32 + kc * 8 + j) * 1024 + ct * 128 + col]);
    *reinterpret_cast<ushort8*>(wb + (((size_t)(ct * 32 + t) * 4 + kc) * 128 + col) * 8) = v;
  }
}

// ---- prep: kernel [16][d][f] f32 -> kt [16][f][d] bf16 ----
__global__ void transpose_k(const float* __restrict__ kin, unsigned short* __restrict__ kt) {
  __shared__ float tile[64][65];
  const int h = blockIdx.x;
  const int t = threadIdx.x;
  #pragma unroll
  for (int i = 0; i < 16; ++i) {
    int idx = i * 256 + t;
    tile[idx >> 6][idx & 63] = kin[(size_t)h * 4096 + idx];
  }
  __syncthreads();
  #pragma unroll
  for (int i = 0; i < 16; ++i) {
    int idx = i * 256 + t;
    kt[(size_t)h * 4096 + idx] = bfbits(tile[idx & 63][idx >> 6]);
  }
}

// ---- main: 4096 blocks x 256 threads; tile 128x128, K=1024, BK=32 ----
__global__ __launch_bounds__(256, 4)
void fused_main(const unsigned short* __restrict__ xb,
                const float* __restrict__ nbias,
                const unsigned short* __restrict__ wb,
                const unsigned short* __restrict__ ktg,
                float* __restrict__ out)
{
  // LDS 32KB: A bufs [0,8K),[8K,16K)   layout [row(128)][slot(4)x16B],
  //           slot swizzled: s' = s ^ ((row>>1)&3)  (2-way frag reads, free)
  //           B bufs [16K,24K),[24K,32K) layout [kc(4)][col(128)][16B]
  // Epilogue reuses [0,16K) as per-wave y (64x64 bf16, XOR-swizzled).
  __shared__ __align__(16) unsigned char smem[32768];
  const int tid = threadIdx.x;
  const int wv = tid >> 6, lane = tid & 63, l15 = lane & 15, lg = lane >> 4;
  const int wr = wv >> 1, wc = wv & 1;            // wave: rows wr*64, cols wc*64
  const int bid = blockIdx.x;
  const int gx = bid & 7, slot = bid >> 3;        // XCD grouping, bijective:
  const int v = gx * 512 + slot;                  // per XCD: 64 rt, ct fastest
  const int rt = v >> 3, ct = v & 7;
  const size_t row0 = (size_t)rt * 128;

  const unsigned char* xrow = reinterpret_cast<const unsigned char*>(xb) + row0 * 2048;
  const unsigned char* wsrc = reinterpret_cast<const unsigned char*>(wb) + (size_t)ct * 262144;

  // A staging: chunk c (0..511) -> r=c>>2, s=c&3; src slot pre-swizzled
  const int c0 = tid,       r0_ = c0 >> 2, s0_ = c0 & 3;
  const int c1 = 256 + tid, r1_ = c1 >> 2;
  const unsigned char* asrc0 = xrow + r0_ * 2048 + ((s0_ ^ ((r0_ >> 1) & 3)) << 4);
  const unsigned char* asrc1 = xrow + r1_ * 2048 + ((s0_ ^ ((r1_ >> 1) & 3)) << 4);

  // fragment-read bases (2-way bank aliasing only)
  const int swz_a = (l15 >> 1) & 3;
  const int abase = (wr * 64 + l15) * 64 + ((lg ^ swz_a) << 4);
  const int bbase = lg * 2048 + (wc * 64 + l15) * 16;

  f32x4 acc[4][4];
  const f32x4 z4 = {0.f, 0.f, 0.f, 0.f};
  #pragma unroll
  for (int mi = 0; mi < 4; ++mi)
    #pragma unroll
    for (int ni = 0; ni < 4; ++ni) acc[mi][ni] = z4;

  auto stageA = [&](int t, int bsel) {
    unsigned char* Ab = smem + (bsel << 13);
    gl_lds16(asrc0 + (size_t)t * 64, Ab + tid * 16);
    gl_lds16(asrc1 + (size_t)t * 64, Ab + 4096 + tid * 16);
  };
  auto stageB = [&](int t, int bsel) {
    unsigned char* Bb = smem + 16384 + (bsel << 13);
    const unsigned char* bs = wsrc + (size_t)t * 8192;
    gl_lds16(bs + tid * 16,        Bb + tid * 16);
    gl_lds16(bs + 4096 + tid * 16, Bb + 4096 + tid * 16);
  };
  auto compute = [&](int csel) {
    const unsigned char* Ab = smem + (csel << 13);
    const unsigned char* Bb = smem + 16384 + (csel << 13);
    bf16x8 af[4], bq[4];
    #pragma unroll
    for (int mi = 0; mi < 4; ++mi)
      af[mi] = *reinterpret_cast<const bf16x8*>(Ab + abase + mi * 1024);
    #pragma unroll
    for (int ni = 0; ni < 4; ++ni)
      bq[ni] = *reinterpret_cast<const bf16x8*>(Bb + bbase + ni * 256);
    __builtin_amdgcn_s_setprio(1);
    #pragma unroll
    for (int mi = 0; mi < 4; ++mi)
      #pragma unroll
      for (int ni = 0; ni < 4; ++ni)
        acc[mi][ni] = mfma_bf16(af[mi], bq[ni], acc[mi][ni]);
    __builtin_amdgcn_s_setprio(0);
  };

  stageA(0, 0);
  stageB(0, 0);

  for (int t = 0; t < 32; ++t) {
    __syncthreads();                       // buf t&1 ready (compiler drains)
    const int cur = t & 1, nxt = cur ^ 1;
    if (t + 1 < 32) { stageA(t + 1, nxt); stageB(t + 1, nxt); }
    compute(cur);                          // overlaps stage(t+1) latency
  }
  __syncthreads();                         // all reads done; reuse LDS as y

  // ---- epilogue: per-head RMSNorm + bias blend -> y LDS -> GEMM2 ----
  const int h = ct * 2 + wc;
  unsigned short* yw = reinterpret_cast<unsigned short*>(smem) + wv * 4096;  // 64x64 swz
  const float* bb = nbias + (row0 + wr * 64) * 1024 + (size_t)h * 64 + l15;

  #pragma unroll
  for (int mi = 0; mi < 4; ++mi) {
    float ss[4];
    #pragma unroll
    for (int r = 0; r < 4; ++r) {
      float p = 0.f;
      #pragma unroll
      for (int ni = 0; ni < 4; ++ni) { const float q = acc[mi][ni][r]; p += q * q; }
      ss[r] = p;
    }
    #pragma unroll
    for (int s = 1; s < 16; s <<= 1)
      #pragma unroll
      for (int r = 0; r < 4; ++r) ss[r] += __shfl_xor(ss[r], s, 64);
    #pragma unroll
    for (int r = 0; r < 4; ++r) {
      const float rs = rsqrtf(ss[r] * 0.015625f + 1e-6f);
      const int rl = mi * 16 + lg * 4 + r;
      const float* bp = bb + (size_t)rl * 1024;
      #pragma unroll
      for (int ni = 0; ni < 4; ++ni) {
        const float y = (acc[mi][ni][r] * rs + bp[ni * 16]) * 0.70710678118654752f;
        yw[rl * 64 + ((ni * 16 + l15) ^ ((rl & 7) << 3))] = bfbits(y);
      }
    }
  }

  // GEMM2: y[64][64] @ ktg[h][f][d]
  const unsigned short* ktp = ktg + (size_t)h * 4096;
  bf16x8 b2[4][2];
  #pragma unroll
  for (int ff = 0; ff < 4; ++ff)
    #pragma unroll
    for (int ks = 0; ks < 2; ++ks)
      b2[ff][ks] = *reinterpret_cast<const bf16x8*>(ktp + (ff * 16 + l15) * 64 + ks * 32 + lg * 8);

  #pragma unroll
  for (int m2 = 0; m2 < 4; ++m2) {
    f32x4 a2[4] = {z4, z4, z4, z4};
    const int row = m2 * 16 + l15;
    #pragma unroll
    for (int ks = 0; ks < 2; ++ks) {
      bf16x8 a = *reinterpret_cast<const bf16x8*>(
          yw + row * 64 + ((ks * 32 + lg * 8) ^ ((row & 7) << 3)));
      #pragma unroll
      for (int ff = 0; ff < 4; ++ff) a2[ff] = mfma_bf16(a, b2[ff][ks], a2[ff]);
    }
    float* ob = out + (row0 + wr * 64 + m2 * 16 + lg * 4) * 1024 + ct * 128 + wc * 64 + l15;
    #pragma unroll
    for (int ff = 0; ff < 4; ++ff)
      #pragma unroll
      for (int r = 0; r < 4; ++r)
        ob[(size_t)r * 1024 + ff * 16] = a2[ff][r];
  }
}

extern "C" void kernel_launch(void* const* d_in, const int* in_sizes, int n_in,
                              void* d_out, int out_size, void* d_ws, size_t ws_size,
                              hipStream_t stream) {
  const float* x  = (const float*)d_in[0];   // [65536][1024]
  const float* nb = (const float*)d_in[1];   // [65536][16][64]
  const float* wl = (const float*)d_in[2];   // [1024][1024]
  const float* kr = (const float*)d_in[3];   // [16][64][64]
  float* out = (float*)d_out;

  unsigned short* wbp = (unsigned short*)d_ws;           // 2 MB blocked W image
  unsigned short* ktp = wbp + 1048576;                   // 128 KB
  unsigned short* xbp = (unsigned short*)((char*)d_ws + 2228224);  // 134 MB bf16 x

  hipLaunchKernelGGL(prep_w2, dim3(32, 8), dim3(128), 0, stream, wl, wbp);
  hipLaunchKernelGGL(transpose_k, dim3(16), dim3(256), 0, stream, kr, ktp);
  hipLaunchKernelGGL(cvt_x, dim3(2048), dim3(256), 0, stream, x, xbp, 65536 * 128);
  hipLaunchKernelGGL(fused_main, dim3(4096), dim3(256), 0, stream, xbp, nb, wbp, ktp, out);
}

// Round 7
// 305.829 us; speedup vs baseline: 1.2809x; 1.0511x over previous
//
#include <hip/hip_runtime.h>

// GroupLinearBlock: out = einsum('nhd,hdf', (rmsnorm_h(x@W) + b)/sqrt2, K)
// R7: m201 8-phase port. cvt x->bf16 prep; GEMM1 = 256x256 tile, BK=64,
// 8 waves (2Mx4N), 128KB LDS dbuf per K-tile, 4 phases/K-tile (one C-quadrant
// x 16 MFMA each), global_load_lds both operands (source-pre-swizzled A,
// prep-image B), per-phase raw barriers + lgkmcnt(0) + setprio, per-K-tile
// vmcnt(0) with 2-phase slack. Fused RMSNorm+bias+GEMM2 epilogue (1 head/wave).

typedef __attribute__((ext_vector_type(8))) __bf16 bf16x8;
typedef __attribute__((ext_vector_type(4))) float f32x4;
typedef __attribute__((ext_vector_type(8))) unsigned short ushort8;

__device__ __forceinline__ unsigned short bfbits(float f) {
  return __builtin_bit_cast(unsigned short, (__bf16)f);
}
__device__ __forceinline__ f32x4 mfma_bf16(bf16x8 a, bf16x8 b, f32x4 c) {
  return __builtin_amdgcn_mfma_f32_16x16x32_bf16(a, b, c, 0, 0, 0);
}
__device__ __forceinline__ void gl_lds16(const void* g, void* l) {
  __builtin_amdgcn_global_load_lds(
      (const __attribute__((address_space(1))) unsigned int*)g,
      (__attribute__((address_space(3))) unsigned int*)l, 16, 0, 0);
}

// ---- prep: x f32 -> xb bf16 ----
__global__ void cvt_x(const float* __restrict__ x, unsigned short* __restrict__ xb, int n8) {
  int i = blockIdx.x * blockDim.x + threadIdx.x;
  const int stride = gridDim.x * blockDim.x;
  for (; i < n8; i += stride) {
    f32x4 a = *reinterpret_cast<const f32x4*>(x + (size_t)i * 8);
    f32x4 b = *reinterpret_cast<const f32x4*>(x + (size_t)i * 8 + 4);
    ushort8 v;
    v[0] = bfbits(a[0]); v[1] = bfbits(a[1]); v[2] = bfbits(a[2]); v[3] = bfbits(a[3]);
    v[4] = bfbits(b[0]); v[5] = bfbits(b[1]); v[6] = bfbits(b[2]); v[7] = bfbits(b[3]);
    *reinterpret_cast<ushort8*>(xb + (size_t)i * 8) = v;
  }
}

// ---- prep: w -> image [ct(4)][ktg(16)][half(2)][16KB] in exact swizzled LDS order
// LDS half-tile: [c(128)][slot(8)x16B], slot s holds k-chunk (s ^ (c&7)).
__global__ void prep_w(const float* __restrict__ w, unsigned short* __restrict__ wb) {
  const int img = blockIdx.x;               // 0..127
  const int ct = img >> 5, ktg = (img >> 1) & 15, half = img & 1;
  #pragma unroll
  for (int i = 0; i < 4; ++i) {
    const int q = i * 256 + threadIdx.x;    // chunk 0..1023
    const int c = q >> 3, s = q & 7;
    const int k0 = ktg * 64 + 8 * (s ^ (c & 7));
    const int col = ct * 256 + half * 128 + c;
    ushort8 v;
    #pragma unroll
    for (int j = 0; j < 8; ++j) v[j] = bfbits(w[(size_t)(k0 + j) * 1024 + col]);
    *reinterpret_cast<ushort8*>(wb + (size_t)img * 8192 + (size_t)q * 8) = v;
  }
}

// ---- prep: kernel [16][d][f] f32 -> kt [16][f][d] bf16 ----
__global__ void transpose_k(const float* __restrict__ kin, unsigned short* __restrict__ kt) {
  __shared__ float tile[64][65];
  const int h = blockIdx.x;
  const int t = threadIdx.x;
  #pragma unroll
  for (int i = 0; i < 16; ++i) {
    int idx = i * 256 + t;
    tile[idx >> 6][idx & 63] = kin[(size_t)h * 4096 + idx];
  }
  __syncthreads();
  #pragma unroll
  for (int i = 0; i < 16; ++i) {
    int idx = i * 256 + t;
    kt[(size_t)h * 4096 + idx] = bfbits(tile[idx & 63][idx >> 6]);
  }
}

// ---- main: 1024 blocks x 512 threads; tile 256x256, K=1024, BK=64 ----
__global__ __launch_bounds__(512, 2)
void fused_main(const unsigned short* __restrict__ xb,
                const float* __restrict__ nbias,
                const unsigned short* __restrict__ wb,
                const unsigned short* __restrict__ ktg_,
                float* __restrict__ out)
{
  // LDS 128KB: A bufs [0,32K),[32K,64K); B bufs [64K,96K),[96K,128K).
  // Each buf = 2 halves x 16KB, half = [r(128)][slot(8)x16B], slot^(r&7) swz.
  // Epilogue reuses all 128KB as per-wave y (128x64 bf16, 16KB/wave).
  __shared__ __align__(16) unsigned char smem[131072];
  const int tid = threadIdx.x;
  const int wv = tid >> 6, lane = tid & 63, l15 = lane & 15, lg = lane >> 4;
  const int l7 = l15 & 7;
  const int wr = wv >> 2, wc = wv & 3;     // wave: rows wr*128, cols wc*64
  const int bid = blockIdx.x;
  const int v = (bid & 7) * 128 + (bid >> 3);   // XCD grouping (1024 % 8 == 0)
  const int rt = v >> 2, ct = v & 3;
  const size_t row0 = (size_t)rt * 256;

  const char* xB = (const char*)xb;
  const char* wB = (const char*)wb + (size_t)ct * 524288;

  // A staging: thread u -> row su (and su+64 / halves), slot ss; src pre-swizzled
  const int su = tid >> 3, ss = tid & 7;
  const char* asrc = xB + (row0 + su) * 2048 + ((ss ^ (su & 7)) << 4);

  // fragment-read byte offsets (2-way bank aliasing only)
  const int aO0 = wr * 16384 + l15 * 128 + ((lg ^ l7) << 4);
  const int aO1 = wr * 16384 + l15 * 128 + (((4 + lg) ^ l7) << 4);
  const int bH  = 65536 + (wc >> 1) * 16384 + ((wc & 1) * 64 + l15) * 128;
  const int bO0 = bH + ((lg ^ l7) << 4);
  const int bO1 = bH + (((4 + lg) ^ l7) << 4);

  f32x4 acc[8][4];
  const f32x4 z4 = {0.f, 0.f, 0.f, 0.f};
  #pragma unroll
  for (int mi = 0; mi < 8; ++mi)
    #pragma unroll
    for (int ni = 0; ni < 4; ++ni) acc[mi][ni] = z4;

  auto stageA2 = [&](int kt, int buf) {          // both halves, 4 gl_lds
    unsigned char* d = smem + (buf << 15) + tid * 16;
    const char* s0 = asrc + (size_t)kt * 128;
    gl_lds16(s0,          d);                    // half0 rows 0..63
    gl_lds16(s0 + 131072, d + 8192);             // half0 rows 64..127
    gl_lds16(s0 + 262144, d + 16384);            // half1 rows 0..63
    gl_lds16(s0 + 393216, d + 24576);            // half1 rows 64..127
  };
  auto stageB2 = [&](int kt, int buf) {          // both halves, 4 gl_lds (flat)
    unsigned char* d = smem + 65536 + (buf << 15) + tid * 16;
    const char* s0 = wB + (size_t)kt * 32768 + tid * 16;
    gl_lds16(s0,         d);
    gl_lds16(s0 + 8192,  d + 8192);
    gl_lds16(s0 + 16384, d + 16384);
    gl_lds16(s0 + 24576, d + 24576);
  };

  // ---- prologue: stage K-tile 0 fully, drain, barrier ----
  stageA2(0, 0);
  stageB2(0, 0);
  asm volatile("s_waitcnt vmcnt(0)" ::: "memory");
  __builtin_amdgcn_s_barrier();

  // ---- K-loop: 16 K-tiles x 4 phases (C-quadrants) ----
  for (int tau = 0; tau < 16; ++tau) {
    const int cb = tau & 1, nb = cb ^ 1;
    const bool st = (tau + 1 < 16);
    const unsigned char* S = smem + (cb << 15);
    bf16x8 alo[4][2], ahi[4][2], blo[2][2], bhi[2][2];

    // phase 0: read A-lo + B-lo; stage A(tau+1); MFMA quadrant (lo,lo)
    #pragma unroll
    for (int m = 0; m < 4; ++m) {
      alo[m][0] = *reinterpret_cast<const bf16x8*>(S + aO0 + m * 2048);
      alo[m][1] = *reinterpret_cast<const bf16x8*>(S + aO1 + m * 2048);
    }
    #pragma unroll
    for (int n = 0; n < 2; ++n) {
      blo[n][0] = *reinterpret_cast<const bf16x8*>(S + bO0 + n * 2048);
      blo[n][1] = *reinterpret_cast<const bf16x8*>(S + bO1 + n * 2048);
    }
    if (st) stageA2(tau + 1, nb);
    __builtin_amdgcn_s_barrier();
    asm volatile("s_waitcnt lgkmcnt(0)" ::: "memory");
    __builtin_amdgcn_s_setprio(1);
    #pragma unroll
    for (int m = 0; m < 4; ++m)
      #pragma unroll
      for (int n = 0; n < 2; ++n)
        acc[m][n] = mfma_bf16(alo[m][1], blo[n][1],
                    mfma_bf16(alo[m][0], blo[n][0], acc[m][n]));
    __builtin_amdgcn_s_setprio(0);
    __builtin_amdgcn_s_barrier();

    // phase 1: read B-hi; stage B(tau+1); MFMA quadrant (lo,hi)
    #pragma unroll
    for (int n = 0; n < 2; ++n) {
      bhi[n][0] = *reinterpret_cast<const bf16x8*>(S + bO0 + (2 + n) * 2048);
      bhi[n][1] = *reinterpret_cast<const bf16x8*>(S + bO1 + (2 + n) * 2048);
    }
    if (st) stageB2(tau + 1, nb);
    __builtin_amdgcn_s_barrier();
    asm volatile("s_waitcnt lgkmcnt(0)" ::: "memory");
    __builtin_amdgcn_s_setprio(1);
    #pragma unroll
    for (int m = 0; m < 4; ++m)
      #pragma unroll
      for (int n = 0; n < 2; ++n)
        acc[m][2 + n] = mfma_bf16(alo[m][1], bhi[n][1],
                        mfma_bf16(alo[m][0], bhi[n][0], acc[m][2 + n]));
    __builtin_amdgcn_s_setprio(0);
    __builtin_amdgcn_s_barrier();

    // phase 2: read A-hi; MFMA quadrant (hi,lo)
    #pragma unroll
    for (int m = 0; m < 4; ++m) {
      ahi[m][0] = *reinterpret_cast<const bf16x8*>(S + aO0 + (4 + m) * 2048);
      ahi[m][1] = *reinterpret_cast<const bf16x8*>(S + aO1 + (4 + m) * 2048);
    }
    __builtin_amdgcn_s_barrier();
    asm volatile("s_waitcnt lgkmcnt(0)" ::: "memory");
    __builtin_amdgcn_s_setprio(1);
    #pragma unroll
    for (int m = 0; m < 4; ++m)
      #pragma unroll
      for (int n = 0; n < 2; ++n)
        acc[4 + m][n] = mfma_bf16(ahi[m][1], blo[n][1],
                        mfma_bf16(ahi[m][0], blo[n][0], acc[4 + m][n]));
    __builtin_amdgcn_s_setprio(0);
    __builtin_amdgcn_s_barrier();

    // phase 3: MFMA quadrant (hi,hi); per-K-tile vmcnt; closing barrier
    __builtin_amdgcn_s_setprio(1);
    #pragma unroll
    for (int m = 0; m < 4; ++m)
      #pragma unroll
      for (int n = 0; n < 2; ++n)
        acc[4 + m][2 + n] = mfma_bf16(ahi[m][1], bhi[n][1],
                            mfma_bf16(ahi[m][0], bhi[n][0], acc[4 + m][2 + n]));
    __builtin_amdgcn_s_setprio(0);
    if (st) asm volatile("s_waitcnt vmcnt(0)" ::: "memory");
    __builtin_amdgcn_s_barrier();
  }
  __syncthreads();   // full drain; repurpose LDS as per-wave y

  // ---- epilogue: per-head RMSNorm + bias blend -> y LDS -> GEMM2 ----
  const int h = ct * 4 + wc;
  unsigned short* yw = reinterpret_cast<unsigned short*>(smem + wv * 16384);  // 128x64
  const float* bb = nbias + (row0 + wr * 128) * 1024 + (size_t)h * 64 + l15;

  #pragma unroll
  for (int mi = 0; mi < 8; ++mi) {
    float ssq[4];
    #pragma unroll
    for (int r = 0; r < 4; ++r) {
      float p = 0.f;
      #pragma unroll
      for (int ni = 0; ni < 4; ++ni) { const float q = acc[mi][ni][r]; p += q * q; }
      ssq[r] = p;
    }
    #pragma unroll
    for (int s = 1; s < 16; s <<= 1)
      #pragma unroll
      for (int r = 0; r < 4; ++r) ssq[r] += __shfl_xor(ssq[r], s, 64);
    #pragma unroll
    for (int r = 0; r < 4; ++r) {
      const float rs = rsqrtf(ssq[r] * 0.015625f + 1e-6f);
      const int rl = mi * 16 + lg * 4 + r;            // row 0..127
      const float* bp = bb + (size_t)rl * 1024;
      #pragma unroll
      for (int ni = 0; ni < 4; ++ni) {
        const float y = (acc[mi][ni][r] * rs + bp[ni * 16]) * 0.70710678118654752f;
        const int sy = (ni * 2 + (l15 >> 3)) ^ (rl & 7);   // swizzled 16B slot
        yw[rl * 64 + sy * 8 + l7] = bfbits(y);
      }
    }
  }
  asm volatile("s_waitcnt lgkmcnt(0)" ::: "memory");   // y writes visible (own wave)

  // GEMM2: y[128][64] @ ktg_[h][f][d]
  const unsigned short* ktp = ktg_ + (size_t)h * 4096;
  bf16x8 b2[4][2];
  #pragma unroll
  for (int ff = 0; ff < 4; ++ff)
    #pragma unroll
    for (int ks = 0; ks < 2; ++ks)
      b2[ff][ks] = *reinterpret_cast<const bf16x8*>(ktp + (ff * 16 + l15) * 64 + ks * 32 + lg * 8);

  #pragma unroll
  for (int m2 = 0; m2 < 8; ++m2) {
    f32x4 a2[4] = {z4, z4, z4, z4};
    const int row = m2 * 16 + l15;
    #pragma unroll
    for (int ks = 0; ks < 2; ++ks) {
      const int sl = ((ks * 4 + lg) ^ l7);
      bf16x8 a = *reinterpret_cast<const bf16x8*>(yw + row * 64 + sl * 8);
      #pragma unroll
      for (int ff = 0; ff < 4; ++ff) a2[ff] = mfma_bf16(a, b2[ff][ks], a2[ff]);
    }
    float* ob = out + (row0 + wr * 128 + m2 * 16 + lg * 4) * 1024 + h * 64 + l15;
    #pragma unroll
    for (int ff = 0; ff < 4; ++ff)
      #pragma unroll
      for (int r = 0; r < 4; ++r)
        ob[(size_t)r * 1024 + ff * 16] = a2[ff][r];
  }
}

extern "C" void kernel_launch(void* const* d_in, const int* in_sizes, int n_in,
                              void* d_out, int out_size, void* d_ws, size_t ws_size,
                              hipStream_t stream) {
  const float* x  = (const float*)d_in[0];   // [65536][1024]
  const float* nb = (const float*)d_in[1];   // [65536][16][64]
  const float* wl = (const float*)d_in[2];   // [1024][1024]
  const float* kr = (const float*)d_in[3];   // [16][64][64]
  float* out = (float*)d_out;

  unsigned short* wbp = (unsigned short*)d_ws;                      // 2 MB W image
  unsigned short* ktp = wbp + 1048576;                              // 128 KB
  unsigned short* xbp = (unsigned short*)((char*)d_ws + 2228224);   // 134 MB bf16 x

  hipLaunchKernelGGL(prep_w, dim3(128), dim3(256), 0, stream, wl, wbp);
  hipLaunchKernelGGL(transpose_k, dim3(16), dim3(256), 0, stream, kr, ktp);
  hipLaunchKernelGGL(cvt_x, dim3(2048), dim3(256), 0, stream, x, xbp, 65536 * 128);
  hipLaunchKernelGGL(fused_main, dim3(1024), dim3(512), 0, stream, xbp, nb, wbp, ktp, out);
}

// Round 8
// 297.851 us; speedup vs baseline: 1.3152x; 1.0268x over previous
//
#include <hip/hip_runtime.h>

// GroupLinearBlock: out = einsum('nhd,hdf', (rmsnorm_h(x@W) + b)/sqrt2, K)
// R8 = R7 with TRUE counted-vmcnt (T4): stage order matched to consumption
// order (B chunks -> A q0,q2 -> A q1,q3), waits vmcnt(4) end-P1 and vmcnt(2)
// end-P3, never 0 in steady state. All layouts/epilogue identical to R7.

typedef __attribute__((ext_vector_type(8))) __bf16 bf16x8;
typedef __attribute__((ext_vector_type(4))) float f32x4;
typedef __attribute__((ext_vector_type(8))) unsigned short ushort8;

__device__ __forceinline__ unsigned short bfbits(float f) {
  return __builtin_bit_cast(unsigned short, (__bf16)f);
}
__device__ __forceinline__ f32x4 mfma_bf16(bf16x8 a, bf16x8 b, f32x4 c) {
  return __builtin_amdgcn_mfma_f32_16x16x32_bf16(a, b, c, 0, 0, 0);
}
__device__ __forceinline__ void gl_lds16(const void* g, void* l) {
  __builtin_amdgcn_global_load_lds(
      (const __attribute__((address_space(1))) unsigned int*)g,
      (__attribute__((address_space(3))) unsigned int*)l, 16, 0, 0);
}

// ---- prep: x f32 -> xb bf16 ----
__global__ void cvt_x(const float* __restrict__ x, unsigned short* __restrict__ xb, int n8) {
  int i = blockIdx.x * blockDim.x + threadIdx.x;
  const int stride = gridDim.x * blockDim.x;
  for (; i < n8; i += stride) {
    f32x4 a = *reinterpret_cast<const f32x4*>(x + (size_t)i * 8);
    f32x4 b = *reinterpret_cast<const f32x4*>(x + (size_t)i * 8 + 4);
    ushort8 v;
    v[0] = bfbits(a[0]); v[1] = bfbits(a[1]); v[2] = bfbits(a[2]); v[3] = bfbits(a[3]);
    v[4] = bfbits(b[0]); v[5] = bfbits(b[1]); v[6] = bfbits(b[2]); v[7] = bfbits(b[3]);
    *reinterpret_cast<ushort8*>(xb + (size_t)i * 8) = v;
  }
}

// ---- prep: w -> image [ct(4)][ktg(16)][half(2)][16KB] in exact swizzled LDS order
// LDS half-tile: [c(128)][slot(8)x16B], slot s holds k-chunk (s ^ (c&7)).
__global__ void prep_w(const float* __restrict__ w, unsigned short* __restrict__ wb) {
  const int img = blockIdx.x;               // 0..127
  const int ct = img >> 5, ktg = (img >> 1) & 15, half = img & 1;
  #pragma unroll
  for (int i = 0; i < 4; ++i) {
    const int q = i * 256 + threadIdx.x;    // chunk 0..1023
    const int c = q >> 3, s = q & 7;
    const int k0 = ktg * 64 + 8 * (s ^ (c & 7));
    const int col = ct * 256 + half * 128 + c;
    ushort8 v;
    #pragma unroll
    for (int j = 0; j < 8; ++j) v[j] = bfbits(w[(size_t)(k0 + j) * 1024 + col]);
    *reinterpret_cast<ushort8*>(wb + (size_t)img * 8192 + (size_t)q * 8) = v;
  }
}

// ---- prep: kernel [16][d][f] f32 -> kt [16][f][d] bf16 ----
__global__ void transpose_k(const float* __restrict__ kin, unsigned short* __restrict__ kt) {
  __shared__ float tile[64][65];
  const int h = blockIdx.x;
  const int t = threadIdx.x;
  #pragma unroll
  for (int i = 0; i < 16; ++i) {
    int idx = i * 256 + t;
    tile[idx >> 6][idx & 63] = kin[(size_t)h * 4096 + idx];
  }
  __syncthreads();
  #pragma unroll
  for (int i = 0; i < 16; ++i) {
    int idx = i * 256 + t;
    kt[(size_t)h * 4096 + idx] = bfbits(tile[idx & 63][idx >> 6]);
  }
}

// ---- main: 1024 blocks x 512 threads; tile 256x256, K=1024, BK=64 ----
__global__ __launch_bounds__(512, 2)
void fused_main(const unsigned short* __restrict__ xb,
                const float* __restrict__ nbias,
                const unsigned short* __restrict__ wb,
                const unsigned short* __restrict__ ktg_,
                float* __restrict__ out)
{
  // LDS 128KB: A bufs [0,32K),[32K,64K); B bufs [64K,96K),[96K,128K).
  // A buf = 4 quarters (8KB: 64 rows x [slot(8)x16B], slot^(r&7) swz).
  // B buf = 4 col-chunks (8KB: 64 cols each), flat image copy.
  __shared__ __align__(16) unsigned char smem[131072];
  const int tid = threadIdx.x;
  const int wv = tid >> 6, lane = tid & 63, l15 = lane & 15, lg = lane >> 4;
  const int l7 = l15 & 7;
  const int wr = wv >> 2, wc = wv & 3;     // wave: rows wr*128, cols wc*64
  const int bid = blockIdx.x;
  const int v = (bid & 7) * 128 + (bid >> 3);   // XCD grouping (1024 % 8 == 0)
  const int rt = v >> 2, ct = v & 3;
  const size_t row0 = (size_t)rt * 256;

  const char* xB = (const char*)xb;
  const char* wB = (const char*)wb + (size_t)ct * 524288;

  // A staging: thread u -> row su (0..63 within quarter), slot ss; src pre-swizzled
  const int su = tid >> 3, ss = tid & 7;
  const char* asrc = xB + (row0 + su) * 2048 + ((ss ^ (su & 7)) << 4);

  // fragment-read byte offsets (2-way bank aliasing only)
  const int aO0 = wr * 16384 + l15 * 128 + ((lg ^ l7) << 4);
  const int aO1 = wr * 16384 + l15 * 128 + (((4 + lg) ^ l7) << 4);
  const int bH  = 65536 + (wc >> 1) * 16384 + ((wc & 1) * 64 + l15) * 128;
  const int bO0 = bH + ((lg ^ l7) << 4);
  const int bO1 = bH + (((4 + lg) ^ l7) << 4);

  f32x4 acc[8][4];
  const f32x4 z4 = {0.f, 0.f, 0.f, 0.f};
  #pragma unroll
  for (int mi = 0; mi < 8; ++mi)
    #pragma unroll
    for (int ni = 0; ni < 4; ++ni) acc[mi][ni] = z4;

  // Staging halves, ordered by consumption:
  auto stageB_lo = [&](int kt, int buf) {          // B chunks 0,1 (cols 0..127)
    unsigned char* d = smem + 65536 + (buf << 15) + tid * 16;
    const char* s0 = wB + (size_t)kt * 32768 + tid * 16;
    gl_lds16(s0,         d);
    gl_lds16(s0 + 8192,  d + 8192);
  };
  auto stageB_hi = [&](int kt, int buf) {          // B chunks 2,3 (cols 128..255)
    unsigned char* d = smem + 65536 + (buf << 15) + tid * 16;
    const char* s0 = wB + (size_t)kt * 32768 + tid * 16;
    gl_lds16(s0 + 16384, d + 16384);
    gl_lds16(s0 + 24576, d + 24576);
  };
  auto stageA_02 = [&](int kt, int buf) {          // A quarters q0 (rows 0-63), q2 (128-191)
    unsigned char* d = smem + (buf << 15) + tid * 16;
    const char* s0 = asrc + (size_t)kt * 128;
    gl_lds16(s0,          d);
    gl_lds16(s0 + 262144, d + 16384);
  };
  auto stageA_13 = [&](int kt, int buf) {          // A quarters q1 (64-127), q3 (192-255)
    unsigned char* d = smem + (buf << 15) + tid * 16;
    const char* s0 = asrc + (size_t)kt * 128;
    gl_lds16(s0 + 131072, d + 8192);
    gl_lds16(s0 + 393216, d + 24576);
  };

  // ---- prologue: stage tile 0 in consumption order; counted wait ----
  stageB_lo(0, 0); stageB_hi(0, 0); stageA_02(0, 0); stageA_13(0, 0);
  asm volatile("s_waitcnt vmcnt(2)" ::: "memory");   // B-all + Aq0,Aq2 landed
  __builtin_amdgcn_s_barrier();

  // ---- K-loop: 16 K-tiles x 4 phases; counted vmcnt, never 0 (except tail) ----
  for (int tau = 0; tau < 16; ++tau) {
    const int cb = tau & 1, nb = cb ^ 1;
    const bool st = (tau + 1 < 16);
    const unsigned char* S = smem + (cb << 15);
    bf16x8 alo[4][2], ahi[4][2], blo[2][2], bhi[2][2];

    // P0: read A-lo + B-lo; stage B chunks 0,1 (t+1); MFMA (lo,lo)
    #pragma unroll
    for (int m = 0; m < 4; ++m) {
      alo[m][0] = *reinterpret_cast<const bf16x8*>(S + aO0 + m * 2048);
      alo[m][1] = *reinterpret_cast<const bf16x8*>(S + aO1 + m * 2048);
    }
    #pragma unroll
    for (int n = 0; n < 2; ++n) {
      blo[n][0] = *reinterpret_cast<const bf16x8*>(S + bO0 + n * 2048);
      blo[n][1] = *reinterpret_cast<const bf16x8*>(S + bO1 + n * 2048);
    }
    if (st) stageB_lo(tau + 1, nb);
    __builtin_amdgcn_s_barrier();
    asm volatile("s_waitcnt lgkmcnt(0)" ::: "memory");
    __builtin_amdgcn_sched_barrier(0);
    __builtin_amdgcn_s_setprio(1);
    #pragma unroll
    for (int m = 0; m < 4; ++m)
      #pragma unroll
      for (int n = 0; n < 2; ++n)
        acc[m][n] = mfma_bf16(alo[m][1], blo[n][1],
                    mfma_bf16(alo[m][0], blo[n][0], acc[m][n]));
    __builtin_amdgcn_s_setprio(0);
    __builtin_amdgcn_s_barrier();

    // P1: read B-hi; stage B chunks 2,3 (t+1); MFMA (lo,hi); wait Aq1,Aq3(t)
    #pragma unroll
    for (int n = 0; n < 2; ++n) {
      bhi[n][0] = *reinterpret_cast<const bf16x8*>(S + bO0 + (2 + n) * 2048);
      bhi[n][1] = *reinterpret_cast<const bf16x8*>(S + bO1 + (2 + n) * 2048);
    }
    if (st) stageB_hi(tau + 1, nb);
    __builtin_amdgcn_s_barrier();
    asm volatile("s_waitcnt lgkmcnt(0)" ::: "memory");
    __builtin_amdgcn_sched_barrier(0);
    __builtin_amdgcn_s_setprio(1);
    #pragma unroll
    for (int m = 0; m < 4; ++m)
      #pragma unroll
      for (int n = 0; n < 2; ++n)
        acc[m][2 + n] = mfma_bf16(alo[m][1], bhi[n][1],
                        mfma_bf16(alo[m][0], bhi[n][0], acc[m][2 + n]));
    __builtin_amdgcn_s_setprio(0);
    if (st) asm volatile("s_waitcnt vmcnt(4)" ::: "memory");  // Aq1,Aq3(tau) landed
    else    asm volatile("s_waitcnt vmcnt(0)" ::: "memory");
    __builtin_amdgcn_s_barrier();

    // P2: read A-hi (q1/q3); stage A q0,q2 (t+1); MFMA (hi,lo)
    #pragma unroll
    for (int m = 0; m < 4; ++m) {
      ahi[m][0] = *reinterpret_cast<const bf16x8*>(S + aO0 + (4 + m) * 2048);
      ahi[m][1] = *reinterpret_cast<const bf16x8*>(S + aO1 + (4 + m) * 2048);
    }
    if (st) stageA_02(tau + 1, nb);
    __builtin_amdgcn_s_barrier();
    asm volatile("s_waitcnt lgkmcnt(0)" ::: "memory");
    __builtin_amdgcn_sched_barrier(0);
    __builtin_amdgcn_s_setprio(1);
    #pragma unroll
    for (int m = 0; m < 4; ++m)
      #pragma unroll
      for (int n = 0; n < 2; ++n)
        acc[4 + m][n] = mfma_bf16(ahi[m][1], blo[n][1],
                        mfma_bf16(ahi[m][0], blo[n][0], acc[4 + m][n]));
    __builtin_amdgcn_s_setprio(0);
    __builtin_amdgcn_s_barrier();

    // P3: stage A q1,q3 (t+1); MFMA (hi,hi); wait B-all+Aq0,Aq2(t+1); barrier
    if (st) stageA_13(tau + 1, nb);
    __builtin_amdgcn_s_setprio(1);
    #pragma unroll
    for (int m = 0; m < 4; ++m)
      #pragma unroll
      for (int n = 0; n < 2; ++n)
        acc[4 + m][2 + n] = mfma_bf16(ahi[m][1], bhi[n][1],
                            mfma_bf16(ahi[m][0], bhi[n][0], acc[4 + m][2 + n]));
    __builtin_amdgcn_s_setprio(0);
    if (st) asm volatile("s_waitcnt vmcnt(2)" ::: "memory");  // B(t+1)+Aq0,Aq2(t+1)
    __builtin_amdgcn_s_barrier();
  }
  __syncthreads();   // full drain; repurpose LDS as per-wave y

  // ---- epilogue: per-head RMSNorm + bias blend -> y LDS -> GEMM2 ----
  const int h = ct * 4 + wc;
  unsigned short* yw = reinterpret_cast<unsigned short*>(smem + wv * 16384);  // 128x64
  const float* bb = nbias + (row0 + wr * 128) * 1024 + (size_t)h * 64 + l15;

  #pragma unroll
  for (int mi = 0; mi < 8; ++mi) {
    float ssq[4];
    #pragma unroll
    for (int r = 0; r < 4; ++r) {
      float p = 0.f;
      #pragma unroll
      for (int ni = 0; ni < 4; ++ni) { const float q = acc[mi][ni][r]; p += q * q; }
      ssq[r] = p;
    }
    #pragma unroll
    for (int s = 1; s < 16; s <<= 1)
      #pragma unroll
      for (int r = 0; r < 4; ++r) ssq[r] += __shfl_xor(ssq[r], s, 64);
    #pragma unroll
    for (int r = 0; r < 4; ++r) {
      const float rs = rsqrtf(ssq[r] * 0.015625f + 1e-6f);
      const int rl = mi * 16 + lg * 4 + r;            // row 0..127
      const float* bp = bb + (size_t)rl * 1024;
      #pragma unroll
      for (int ni = 0; ni < 4; ++ni) {
        const float y = (acc[mi][ni][r] * rs + bp[ni * 16]) * 0.70710678118654752f;
        const int sy = (ni * 2 + (l15 >> 3)) ^ (rl & 7);   // swizzled 16B slot
        yw[rl * 64 + sy * 8 + l7] = bfbits(y);
      }
    }
  }
  asm volatile("s_waitcnt lgkmcnt(0)" ::: "memory");   // y writes visible (own wave)

  // GEMM2: y[128][64] @ ktg_[h][f][d]
  const unsigned short* ktp = ktg_ + (size_t)h * 4096;
  bf16x8 b2[4][2];
  #pragma unroll
  for (int ff = 0; ff < 4; ++ff)
    #pragma unroll
    for (int ks = 0; ks < 2; ++ks)
      b2[ff][ks] = *reinterpret_cast<const bf16x8*>(ktp + (ff * 16 + l15) * 64 + ks * 32 + lg * 8);

  #pragma unroll
  for (int m2 = 0; m2 < 8; ++m2) {
    f32x4 a2[4] = {z4, z4, z4, z4};
    const int row = m2 * 16 + l15;
    #pragma unroll
    for (int ks = 0; ks < 2; ++ks) {
      const int sl = ((ks * 4 + lg) ^ l7);
      bf16x8 a = *reinterpret_cast<const bf16x8*>(yw + row * 64 + sl * 8);
      #pragma unroll
      for (int ff = 0; ff < 4; ++ff) a2[ff] = mfma_bf16(a, b2[ff][ks], a2[ff]);
    }
    float* ob = out + (row0 + wr * 128 + m2 * 16 + lg * 4) * 1024 + h * 64 + l15;
    #pragma unroll
    for (int ff = 0; ff < 4; ++ff)
      #pragma unroll
      for (int r = 0; r < 4; ++r)
        ob[(size_t)r * 1024 + ff * 16] = a2[ff][r];
  }
}

extern "C" void kernel_launch(void* const* d_in, const int* in_sizes, int n_in,
                              void* d_out, int out_size, void* d_ws, size_t ws_size,
                              hipStream_t stream) {
  const float* x  = (const float*)d_in[0];   // [65536][1024]
  const float* nb = (const float*)d_in[1];   // [65536][16][64]
  const float* wl = (const float*)d_in[2];   // [1024][1024]
  const float* kr = (const float*)d_in[3];   // [16][64][64]
  float* out = (float*)d_out;

  unsigned short* wbp = (unsigned short*)d_ws;                      // 2 MB W image
  unsigned short* ktp = wbp + 1048576;                              // 128 KB
  unsigned short* xbp = (unsigned short*)((char*)d_ws + 2228224);   // 134 MB bf16 x

  hipLaunchKernelGGL(prep_w, dim3(128), dim3(256), 0, stream, wl, wbp);
  hipLaunchKernelGGL(transpose_k, dim3(16), dim3(256), 0, stream, kr, ktp);
  hipLaunchKernelGGL(cvt_x, dim3(2048), dim3(256), 0, stream, x, xbp, 65536 * 128);
  hipLaunchKernelGGL(fused_main, dim3(1024), dim3(512), 0, stream, xbp, nb, wbp, ktp, out);
}